// Round 4
// baseline (81.123 us; speedup 1.0000x reference)
//
#include <hip/hip_runtime.h>

// DBSCAN neighbor-count + classify, MI355X (gfx950). B=4, N=8192, D=16.
// dist(i,j) < EPS=0.5  <=>  x_i.x_j - g_i - g_j > 0,  g_p = 0.5*||x_p||^2 - EPS^2/4
//
// R17: switch the Gram core 16x16x32 (K-augmented) -> 32x32x16 (K=16 native,
// m119: 8.07cyc/1024 results = 2.4x results/cyc). Thresholds move from the
// augmented-K columns into the MFMA C-operand: cin[reg] = -(g_row + g_col),
// so acc>0 is the neighbor test. Matrix pipe 8.3 -> 3.4 us; B-reads halve
// per result and are bank-volume-minimal; staging 24.6 -> 18 KB; no dead
// lanes. Skeleton (2048 blocks, window LDS DMA, rare-positive gate, atomic
// partials, classify) = R14/R16 proven structure.
// aug2 layout: [b][p][16 bf16] (32 B records). garr: [b][p] f32 (= +g).

constexpr int Np = 8192;
constexpr int Bb = 4;
constexpr int MIN_PTS = 10;
constexpr float EPS2_4 = 0.0625f;  // EPS^2 / 4
constexpr int JS = 16;         // j-windows per batch
constexpr int JW = Np / JS;    // 512 j per window/block
constexpr int ICH = 256;       // i rows per block (4 waves x 64)
constexpr int NT = JW / 32;    // 16 j-tiles (32 cols) per window

typedef __bf16 bf16x8 __attribute__((ext_vector_type(8)));
typedef float  f32x16 __attribute__((ext_vector_type(16)));

#define GLOBAL_LOAD_LDS16(gptr, lptr)                                          \
    __builtin_amdgcn_global_load_lds(                                          \
        (const __attribute__((address_space(1))) void*)(gptr),                 \
        (__attribute__((address_space(3))) void*)(lptr), 16, 0, 0)

// ---------------- prep: fp32 -> bf16 records + fp32 g array + zero out -----
__global__ __launch_bounds__(256)
void dbscan_prep(const float* __restrict__ x, __bf16* __restrict__ aug,
                 float* __restrict__ garr, int* __restrict__ out) {
    const int p = blockIdx.x * 256 + threadIdx.x;    // 32768 points
    const float4* src = (const float4*)(x + (size_t)p * 16);
    float4 v0 = src[0], v1 = src[1], v2 = src[2], v3 = src[3];
    float vv[16];
    vv[0]=v0.x; vv[1]=v0.y; vv[2]=v0.z; vv[3]=v0.w;
    vv[4]=v1.x; vv[5]=v1.y; vv[6]=v1.z; vv[7]=v1.w;
    vv[8]=v2.x; vv[9]=v2.y; vv[10]=v2.z; vv[11]=v2.w;
    vv[12]=v3.x; vv[13]=v3.y; vv[14]=v3.z; vv[15]=v3.w;
    float s = 0.f;
#pragma unroll
    for (int k = 0; k < 16; k++) s = fmaf(vv[k], vv[k], s);
    bf16x8 h0, h1;
#pragma unroll
    for (int k = 0; k < 8; k++) { h0[k] = (__bf16)vv[k]; h1[k] = (__bf16)vv[k+8]; }
    bf16x8* dst = (bf16x8*)(aug + (size_t)p * 16);
    dst[0] = h0; dst[1] = h1;
    garr[p] = 0.5f * s - EPS2_4;
    out[p] = 0;
}

// ---------------- count: 32x32x16 Gram sweep, thresholds in C-operand ------
// grid: 4 b x 32 i-chunks x 16 j-windows = 2048 blocks, 256 threads.
__global__ __launch_bounds__(256, 4)
void dbscan_count(const __bf16* __restrict__ aug, const float* __restrict__ garr,
                  int* __restrict__ out) {
    const int lane = threadIdx.x & 63;
    const int w    = threadIdx.x >> 6;
    const int c31  = lane & 31;          // A row / B col within 32-tile
    const int h    = lane >> 5;          // k-half (k = h*8 + e)
    const int blk  = blockIdx.x;
    const int b    = blk >> 9;
    const int ic   = (blk >> 4) & 31;
    const int js   = blk & 15;
    const int ibase = ic * ICH;
    const int jbase = js * JW;
    const size_t pb = (size_t)b * Np;

    // LDS: window points [512][16 bf16] = 16 KB + g-window [512] f32 = 2 KB.
    __shared__ __align__(16) __bf16 ldsW[JW * 16];
    __shared__ __align__(16) float  ldsG[JW];

    // Stage window: pure linear DMA. 1024 + 128 16B-chunks.
    {
        const __bf16* srcW = aug + (pb + jbase) * 16;
#pragma unroll
        for (int it = 0; it < 4; it++) {
            const int c = threadIdx.x + it * 256;
            GLOBAL_LOAD_LDS16(srcW + (size_t)c * 8, ldsW + (size_t)c * 8);
        }
        const float* srcG = garr + pb + jbase;
        if (threadIdx.x < 128)
            GLOBAL_LOAD_LDS16(srcG + threadIdx.x * 4, ldsG + threadIdx.x * 4);
    }

    // A fragments: wave owns 64 rows (2 frags x 32). row = c31, k = h*8+e.
    const int rb = ibase + w * 64;
    bf16x8 af[2];
#pragma unroll
    for (int f = 0; f < 2; f++)
        af[f] = *(const bf16x8*)(aug + (pb + rb + f * 32 + c31) * 16 + h * 8);

    // Negated row-g: C row = (reg&3) + 8*(reg>>2) + 4*h.
    float ngrow[2][16];
#pragma unroll
    for (int f = 0; f < 2; f++)
#pragma unroll
        for (int r = 0; r < 16; r++) {
            const int row = (r & 3) + 8 * (r >> 2) + 4 * h;
            ngrow[f][r] = -garr[pb + rb + f * 32 + row];
        }

    __syncthreads();   // drains vmcnt(0): DMA staging complete

    // Packed counts: frag0 in lo16, frag1 in hi16 (max 512 each, no overflow)
    unsigned int cnt[16];
#pragma unroll
    for (int r = 0; r < 16; r++) cnt[r] = 0u;

    for (int t = 0; t < NT; t++) {
        const bf16x8 bc = *(const bf16x8*)(ldsW + ((t * 32 + c31) * 16 + h * 8));
        const float  gc = ldsG[t * 32 + c31];
#pragma unroll
        for (int f = 0; f < 2; f++) {
            f32x16 cin;
#pragma unroll
            for (int r = 0; r < 16; r++) cin[r] = ngrow[f][r] - gc;
            f32x16 acc = __builtin_amdgcn_mfma_f32_32x32x16_bf16(af[f], bc, cin, 0, 0, 0);
            // Rare-positive gate (neighbors ~ diagonal-only for this data).
            float mx = acc[0];
#pragma unroll
            for (int r = 1; r < 16; r++) mx = fmaxf(mx, acc[r]);
            if (__ballot(mx > 0.0f) != 0ull) {     // wave-uniform, rare
                const unsigned int step = f ? 0x10000u : 1u;
#pragma unroll
                for (int r = 0; r < 16; r++)
                    cnt[r] += (acc[r] > 0.0f) ? step : 0u;
            }
        }
    }

    // Sum across 32 cols (lane bits 0..4); packed fields sum independently.
#pragma unroll
    for (int r = 0; r < 16; r++) {
        unsigned int v = cnt[r];
        v += __shfl_xor(v, 1);
        v += __shfl_xor(v, 2);
        v += __shfl_xor(v, 4);
        v += __shfl_xor(v, 8);
        v += __shfl_xor(v, 16);
        cnt[r] = v;
    }
    if (c31 == 0) {        // lanes 0 (h=0) and 32 (h=1)
        int* ob = out + pb + rb;
#pragma unroll
        for (int r = 0; r < 16; r++) {
            const int row = (r & 3) + 8 * (r >> 2) + 4 * h;
            atomicAdd(&ob[row],      (int)(cnt[r] & 0xffffu));
            atomicAdd(&ob[32 + row], (int)(cnt[r] >> 16));
        }
    }
}

// ---------------- classify ----------------
__global__ __launch_bounds__(256)
void dbscan_classify(int* __restrict__ out) {
    const int p = blockIdx.x * 256 + threadIdx.x;
    out[p] = (out[p] < MIN_PTS) ? -1 : 0;
}

extern "C" void kernel_launch(void* const* d_in, const int* in_sizes, int n_in,
                              void* d_out, int out_size, void* d_ws, size_t ws_size,
                              hipStream_t stream) {
    const float* x = (const float*)d_in[0];
    int* out = (int*)d_out;
    __bf16* aug = (__bf16*)d_ws;                       // 32768*32 B = 1 MB
    float* garr = (float*)((char*)d_ws + (1u << 20));  // 32768*4 B = 128 KB

    dbscan_prep<<<dim3(Bb * Np / 256), dim3(256), 0, stream>>>(x, aug, garr, out);
    dbscan_count<<<dim3(Bb * 32 * JS), dim3(256), 0, stream>>>(aug, garr, out);
    dbscan_classify<<<dim3(Bb * Np / 256), dim3(256), 0, stream>>>(out);
}